// Round 6
// baseline (30.445 us; speedup 1.0000x reference)
//
#include <hip/hip_runtime.h>

// PointsNonMaxSuppression: out = (maxpool3x3_same(points) == points) ? points : 0
// points: [B=16, C=80, H=128, W=128] float32.
//
// Separable max. Each thread owns a 4-column (float4) strip of one (b,c)
// plane over a TILE_H-row tile. Per row: one coalesced float4 load,
// horizontal 3-max via wave shuffles, sliding 3-row vertical max in
// registers, one nontemporal float4 store.
//
// R5 post-mortem: at TILE_H=8 the fabric moves ~189 MB (1.25x read halo) at
// ~6.4 TB/s -- we're AT the mixed-stream ceiling, so shrink moved bytes.
// TILE_H=32 cuts read amplification to 1.0625x (34 rows per 32). NT stores
// (R5 win) keep the write-once output from evicting the L3-resident input.

#define TILE_H 32
#define W 128
#define H 128

typedef float floatx4 __attribute__((ext_vector_type(4)));

__device__ __forceinline__ float max3f(float a, float b, float c) {
    return fmaxf(fmaxf(a, b), c);
}

__device__ __forceinline__ float4 hrow_max(float4 v, int g) {
    // horizontal 3-max with neighbors from adjacent lanes
    float left  = __shfl_up(v.w, 1);   // lane g-1's col 4g-1
    float right = __shfl_down(v.x, 1); // lane g+1's col 4g+4
    if (g == 0)  left  = -__builtin_inff();
    if (g == 31) right = -__builtin_inff();
    float4 h;
    h.x = max3f(left, v.x, v.y);
    h.y = max3f(v.x, v.y, v.z);
    h.z = max3f(v.y, v.z, v.w);
    h.w = max3f(v.z, v.w, right);
    return h;
}

__global__ __launch_bounds__(256) void nms3x3_kernel(const float* __restrict__ in,
                                                     float* __restrict__ out) {
    const int tid = blockIdx.x * 256 + threadIdx.x;
    const int g = tid & 31;      // column group (4 cols each): 32 groups cover W=128
    const int s = tid >> 5;      // strip id
    const int t = s & 3;         // row-tile within plane (H / TILE_H = 4)
    const int p = s >> 2;        // plane index b*C + c
    const int y0 = t * TILE_H;

    const float* __restrict__ pin  = in  + (size_t)p * (H * W) + g * 4;
    float*       __restrict__ pout = out + (size_t)p * (H * W) + g * 4;

    const float NEG_INF = -__builtin_inff();
    const float4 ninf4 = make_float4(NEG_INF, NEG_INF, NEG_INF, NEG_INF);

    float4 hm_prev, hm_cur, hm_next;
    float4 c_cur, c_next;

    // row y0-1 (halo above) -- clamp address, select -inf; branch-free so all
    // 64 lanes stay active for the shuffles.
    {
        int y = y0 - 1;
        int yc = (y < 0) ? 0 : y;
        float4 v = *reinterpret_cast<const float4*>(pin + yc * W);
        if (y < 0) v = ninf4;
        hm_prev = hrow_max(v, g);
    }
    // row y0
    {
        float4 v = *reinterpret_cast<const float4*>(pin + y0 * W);
        c_cur = v;
        hm_cur = hrow_max(v, g);
    }

#pragma unroll 8
    for (int r = 0; r < TILE_H; ++r) {
        int y = y0 + r + 1;
        int yc = (y >= H) ? (H - 1) : y;
        float4 v = *reinterpret_cast<const float4*>(pin + yc * W);
        if (y >= H) v = ninf4;
        c_next  = v;
        hm_next = hrow_max(v, g);

        floatx4 o;
        o.x = (max3f(hm_prev.x, hm_cur.x, hm_next.x) == c_cur.x) ? c_cur.x : 0.0f;
        o.y = (max3f(hm_prev.y, hm_cur.y, hm_next.y) == c_cur.y) ? c_cur.y : 0.0f;
        o.z = (max3f(hm_prev.z, hm_cur.z, hm_next.z) == c_cur.z) ? c_cur.z : 0.0f;
        o.w = (max3f(hm_prev.w, hm_cur.w, hm_next.w) == c_cur.w) ? c_cur.w : 0.0f;
        __builtin_nontemporal_store(o, reinterpret_cast<floatx4*>(pout + (y0 + r) * W));

        hm_prev = hm_cur;
        hm_cur  = hm_next;
        c_cur   = c_next;
    }
}

extern "C" void kernel_launch(void* const* d_in, const int* in_sizes, int n_in,
                              void* d_out, int out_size, void* d_ws, size_t ws_size,
                              hipStream_t stream) {
    const float* in = (const float*)d_in[0];
    float* out = (float*)d_out;

    // B*C = 16*80 = 1280 planes, 4 row-tiles each, 32 lanes per row-tile
    const int planes = 1280;
    const int strips = planes * (H / TILE_H);     // 5120
    const int total_threads = strips * 32;        // 163840
    const int blocks = total_threads / 256;       // 640

    nms3x3_kernel<<<blocks, 256, 0, stream>>>(in, out);
}

// Round 7
// 29.330 us; speedup vs baseline: 1.0380x; 1.0380x over previous
//
#include <hip/hip_runtime.h>

// PointsNonMaxSuppression: out = (maxpool3x3_same(points) == points) ? points : 0
// points: [B=16, C=80, H=128, W=128] float32.
//
// Separable max, explicit-prefetch version. Each thread owns a 4-column
// (float4) strip of one (b,c) plane over TILE_H=8 rows. Phase 1: issue all
// 10 row loads (8 + 2 halo) back-to-back -> 10 loads in flight per wave
// (R6 post-mortem: sliding-window loop kept only ~2 in flight, VGPR=32,
// exposed read latency). Phase 2: horizontal 3-max via wave shuffles,
// vertical 3-max, compare, NT store (write-once output must not evict the
// L3-resident input; NT = R5's +2.6%).

#define TILE_H 8
#define W 128
#define H 128

typedef float floatx4 __attribute__((ext_vector_type(4)));

__device__ __forceinline__ float max3f(float a, float b, float c) {
    return fmaxf(fmaxf(a, b), c);
}

__device__ __forceinline__ float4 hrow_max(float4 v, int g) {
    // horizontal 3-max with neighbors from adjacent lanes
    float left  = __shfl_up(v.w, 1);   // lane g-1's col 4g-1
    float right = __shfl_down(v.x, 1); // lane g+1's col 4g+4
    if (g == 0)  left  = -__builtin_inff();
    if (g == 31) right = -__builtin_inff();
    float4 h;
    h.x = max3f(left, v.x, v.y);
    h.y = max3f(v.x, v.y, v.z);
    h.z = max3f(v.y, v.z, v.w);
    h.w = max3f(v.z, v.w, right);
    return h;
}

__global__ __launch_bounds__(256) void nms3x3_kernel(const float* __restrict__ in,
                                                     float* __restrict__ out) {
    const int tid = blockIdx.x * 256 + threadIdx.x;
    const int g = tid & 31;      // column group (4 cols each): 32 groups cover W=128
    const int s = tid >> 5;      // strip id
    const int t = s & 15;        // row-tile within plane (H / TILE_H = 16)
    const int p = s >> 4;        // plane index b*C + c
    const int y0 = t * TILE_H;

    const float* __restrict__ pin  = in  + (size_t)p * (H * W) + g * 4;
    float*       __restrict__ pout = out + (size_t)p * (H * W) + g * 4;

    const float NEG_INF = -__builtin_inff();
    const float4 ninf4 = make_float4(NEG_INF, NEG_INF, NEG_INF, NEG_INF);

    // Phase 1: issue all TILE_H+2 row loads back-to-back (max MLP).
    float4 v[TILE_H + 2];
#pragma unroll
    for (int i = 0; i < TILE_H + 2; ++i) {
        int y = y0 - 1 + i;
        int yc = (y < 0) ? 0 : ((y >= H) ? (H - 1) : y);
        v[i] = *reinterpret_cast<const float4*>(pin + yc * W);
    }
    // halo rows outside the plane contribute -inf (t is uniform per 32-group;
    // per-lane cndmask, no divergence cost)
    if (t == 0)  v[0] = ninf4;
    if (t == 15) v[TILE_H + 1] = ninf4;

    // Phase 2: horizontal 3-max per row, then vertical 3-max + compare + store.
    float4 hm[TILE_H + 2];
#pragma unroll
    for (int i = 0; i < TILE_H + 2; ++i) {
        hm[i] = hrow_max(v[i], g);
    }

#pragma unroll
    for (int r = 0; r < TILE_H; ++r) {
        const float4 c = v[r + 1];
        floatx4 o;
        o.x = (max3f(hm[r].x, hm[r + 1].x, hm[r + 2].x) == c.x) ? c.x : 0.0f;
        o.y = (max3f(hm[r].y, hm[r + 1].y, hm[r + 2].y) == c.y) ? c.y : 0.0f;
        o.z = (max3f(hm[r].z, hm[r + 1].z, hm[r + 2].z) == c.z) ? c.z : 0.0f;
        o.w = (max3f(hm[r].w, hm[r + 1].w, hm[r + 2].w) == c.w) ? c.w : 0.0f;
        __builtin_nontemporal_store(o, reinterpret_cast<floatx4*>(pout + (y0 + r) * W));
    }
}

extern "C" void kernel_launch(void* const* d_in, const int* in_sizes, int n_in,
                              void* d_out, int out_size, void* d_ws, size_t ws_size,
                              hipStream_t stream) {
    const float* in = (const float*)d_in[0];
    float* out = (float*)d_out;

    // B*C = 16*80 = 1280 planes, 16 row-tiles each, 32 lanes per row-tile
    const int planes = 1280;
    const int strips = planes * (H / TILE_H);     // 20480
    const int total_threads = strips * 32;        // 655360
    const int blocks = total_threads / 256;       // 2560

    nms3x3_kernel<<<blocks, 256, 0, stream>>>(in, out);
}